// Round 14
// baseline (222.422 us; speedup 1.0000x reference)
//
#include <hip/hip_runtime.h>
#include <hip/hip_bf16.h>

// SDPA with bias, materializing output + attention weights.
// B=4, H=8, T=2048, DK=64, fp32 in/out, bf16 MFMA 16x16x32 inside.
// Round 14: split into two kernels. Kernel A (l-compute) = r12 phase 1:
// QB=64, 4 q-waves x 2 k-groups, grid 1024x8waves = 100% occupancy cap,
// LDS 18.4KB; writes l[bh][q] to d_ws. Kernel B = r13 phase 2 verbatim,
// reads inv_l once. r13's phase 1 ran grid-capped at 50% occupancy with
// 55KB LDS it didn't need; A gets 4 blocks/CU. NT W/O stores kept (r13 win).
#define TT   2048
#define DKK  64
#define NHH  8
#define NBB  4
#define KBLK 64
#define NKT  (TT / KBLK)   // 32
#define LDE  72            // padded LDS row stride: bank-uniform for frag reads
#define TILE (KBLK * LDE)
#define SCALE 0.125f

// LDS-only barrier: waits own ds ops, syncs waves, does NOT drain vmcnt
#define SOFT_BARRIER() do {                                         \
    asm volatile("s_waitcnt lgkmcnt(0)" ::: "memory");              \
    __builtin_amdgcn_s_barrier();                                   \
    asm volatile("" ::: "memory");                                  \
} while (0)

typedef __attribute__((ext_vector_type(4))) float  f32x4;
typedef __attribute__((ext_vector_type(8))) __bf16 bf16x8;
typedef __attribute__((ext_vector_type(4))) __bf16 bf16x4;

// ---- prepass 1: K fp32 -> bf16, same [bh][t][d] layout ----
__global__ __launch_bounds__(256)
void cast_k_kernel(const float* __restrict__ K, __bf16* __restrict__ Kb) {
    size_t i = ((size_t)blockIdx.x * 256 + threadIdx.x) * 8;
    f32x4 a = *(const f32x4*)(K + i);
    f32x4 b = *(const f32x4*)(K + i + 4);
    bf16x8 o = {(__bf16)a[0], (__bf16)a[1], (__bf16)a[2], (__bf16)a[3],
                (__bf16)b[0], (__bf16)b[1], (__bf16)b[2], (__bf16)b[3]};
    *(bf16x8*)(Kb + i) = o;
}

// ---- prepass 2: V fp32 [bh][t][d] -> bf16 transposed [bh][d][t] ----
__global__ __launch_bounds__(256)
void vt_kernel(const float* __restrict__ V, __bf16* __restrict__ Vt) {
    __shared__ __bf16 tile[DKK][72];
    const int bh = blockIdx.y;
    const int t0 = blockIdx.x * 64;
    const int tid = threadIdx.x;
    const float* Vb = V + ((size_t)bh * TT + t0) * DKK;
    #pragma unroll
    for (int i = 0; i < 4; ++i) {
        int idx = tid + i * 256;
        int row = idx >> 4, c4 = idx & 15;
        f32x4 v = *(const f32x4*)(Vb + row * DKK + c4 * 4);
        tile[c4 * 4 + 0][row] = (__bf16)v[0];
        tile[c4 * 4 + 1][row] = (__bf16)v[1];
        tile[c4 * 4 + 2][row] = (__bf16)v[2];
        tile[c4 * 4 + 3][row] = (__bf16)v[3];
    }
    __syncthreads();
    __bf16* out = Vt + (size_t)bh * DKK * TT + t0;
    #pragma unroll
    for (int i = 0; i < 2; ++i) {
        int idx = tid + i * 256;
        int d = idx >> 3, ch = idx & 7;
        bf16x8 o = *(const bf16x8*)&tile[d][ch * 8];
        *(bf16x8*)(out + (size_t)d * TT + ch * 8) = o;
    }
}

// ================== kernel A: l[bh][q] = sum_k exp(s) ====================
// QB=64: 4 q-waves x 2 k-groups; grid 1024 blocks x 8 waves = 8192 waves.
__global__ __launch_bounds__(512, 8)
void lsum_kernel(const float* __restrict__ Qp, const float* __restrict__ Bp,
                 const __bf16* __restrict__ Kb, float* __restrict__ Lp)
{
    __shared__ __bf16 Kl[2][TILE];   // K tile double buffer [key][d]
    __shared__ float  Sst[8][16];    // per-wave per-q partial l

    const int tid  = threadIdx.x;
    const int lane = tid & 63;
    const int w    = tid >> 6;     // 0..7
    const int kg   = w >> 2;       // k-group 0/1: keys kg*32..+31 of the tile
    const int qw   = w & 3;        // q-wave: rows qw*16..+15
    const int g    = lane >> 4;    // 0..3
    const int ql   = lane & 15;

    const int id  = blockIdx.x;    // 0..1023
    const int h   = id & 7;        // XCD-aware: one head's bias per XCD
    const int r   = id >> 3;       // 0..127
    const int qt  = r & 31;        // 0..31
    const int b   = r >> 5;        // 0..3
    const int bh  = b * NHH + h;

    const int q_local = qw * 16 + ql;
    const int q_glob  = qt * 64 + q_local;

    const __bf16* Kbh = Kb + (size_t)bh * TT * DKK;
    const float* biasRow = Bp + ((size_t)h * TT + q_glob) * TT;

    const int srow = tid >> 3;     // staging: 0..63
    const int sch  = tid & 7;      // staging: 0..7

    // Q fragments (B-operand)
    const float* qrow = Qp + ((size_t)bh * TT + q_glob) * DKK;
    f32x4 qa = *(const f32x4*)(qrow + g * 8);
    f32x4 qc = *(const f32x4*)(qrow + g * 8 + 4);
    f32x4 qe = *(const f32x4*)(qrow + 32 + g * 8);
    f32x4 qf = *(const f32x4*)(qrow + 32 + g * 8 + 4);
    const bf16x8 qfrag0 = {(__bf16)qa[0], (__bf16)qa[1], (__bf16)qa[2], (__bf16)qa[3],
                           (__bf16)qc[0], (__bf16)qc[1], (__bf16)qc[2], (__bf16)qc[3]};
    const bf16x8 qfrag1 = {(__bf16)qe[0], (__bf16)qe[1], (__bf16)qe[2], (__bf16)qe[3],
                           (__bf16)qf[0], (__bf16)qf[1], (__bf16)qf[2], (__bf16)qf[3]};

    *(bf16x8*)&Kl[0][srow * LDE + sch * 8] =
        *(const bf16x8*)(Kbh + (size_t)srow * DKK + sch * 8);
    __syncthreads();

    f32x4 lacc = {0.f, 0.f, 0.f, 0.f};
    for (int kt = 0; kt < NKT; ++kt) {
        const int cur = kt & 1;
        const bool more = (kt + 1 < NKT);
        bf16x8 kreg;
        if (more)
            kreg = *(const bf16x8*)(Kbh + ((size_t)(kt + 1) * KBLK + srow) * DKK + sch * 8);
        const float* bp = biasRow + kt * KBLK + kg * 32;
        f32x4 bv[2];
        #pragma unroll
        for (int s = 0; s < 2; ++s) bv[s] = *(const f32x4*)(bp + s * 16 + g * 4);

        f32x4 acc[2] = {};
        #pragma unroll
        for (int s = 0; s < 2; ++s) {
            const int krow = (kg * 2 + s) * 16 + ql;
            bf16x8 a0 = *(const bf16x8*)&Kl[cur][krow * LDE + g * 8];
            acc[s] = __builtin_amdgcn_mfma_f32_16x16x32_bf16(a0, qfrag0, acc[s], 0, 0, 0);
            bf16x8 a1 = *(const bf16x8*)&Kl[cur][krow * LDE + 32 + g * 8];
            acc[s] = __builtin_amdgcn_mfma_f32_16x16x32_bf16(a1, qfrag1, acc[s], 0, 0, 0);
        }
        #pragma unroll
        for (int s = 0; s < 2; ++s) {
            f32x4 x = acc[s] * SCALE + bv[s];
            lacc[0] += __expf(x[0]);
            lacc[1] += __expf(x[1]);
            lacc[2] += __expf(x[2]);
            lacc[3] += __expf(x[3]);
        }
        if (more)
            *(bf16x8*)&Kl[cur ^ 1][srow * LDE + sch * 8] = kreg;
        SOFT_BARRIER();
    }
    float l_run = lacc[0] + lacc[1] + lacc[2] + lacc[3];
    l_run += __shfl_xor(l_run, 16);
    l_run += __shfl_xor(l_run, 32);
    if (g == 0) Sst[w][ql] = l_run;
    __syncthreads();
    l_run += Sst[w ^ 4][ql];
    if (kg == 0 && g == 0)
        Lp[(size_t)bh * TT + q_glob] = l_run;
}

// ================== kernel B: weights + PV (r13 phase 2) =================
__global__ __launch_bounds__(512, 4)
void sdpa_main(const float* __restrict__ Qp, const float* __restrict__ Bp,
               const __bf16* __restrict__ Kb, const __bf16* __restrict__ Vt,
               const float* __restrict__ Lp,
               float* __restrict__ Op, float* __restrict__ Wp)
{
    __shared__ __bf16 Kl[2][TILE];     // K tile double buffer [key][d]
    __shared__ __bf16 Vl[2][TILE];     // V^T tile double buffer [d][key]
    __shared__ __bf16 Pl[8][16 * LDE]; // wave-private P [q][key]

    const int tid  = threadIdx.x;
    const int lane = tid & 63;
    const int w    = tid >> 6;     // 0..7 : q rows w*16..+15
    const int g    = lane >> 4;    // 0..3
    const int ql   = lane & 15;

    const int id  = blockIdx.x;    // 0..511
    const int h   = id & 7;
    const int r   = id >> 3;       // 0..63
    const int qt  = r & 15;        // 0..15
    const int b   = r >> 4;        // 0..3
    const int bh  = b * NHH + h;

    const int q_local = w * 16 + ql;
    const int q_glob  = qt * 128 + q_local;

    const __bf16* Kbh = Kb + (size_t)bh * TT * DKK;   // [key][d]
    const __bf16* Vbh = Vt + (size_t)bh * DKK * TT;   // [d][key]
    const float* biasRow = Bp + ((size_t)h * TT + q_glob) * TT;

    const int srow = tid >> 3;     // 0..63
    const int sch  = tid & 7;      // 0..7

    // Q fragments (B-operand)
    const float* qrow = Qp + ((size_t)bh * TT + q_glob) * DKK;
    f32x4 qa = *(const f32x4*)(qrow + g * 8);
    f32x4 qc = *(const f32x4*)(qrow + g * 8 + 4);
    f32x4 qe = *(const f32x4*)(qrow + 32 + g * 8);
    f32x4 qf = *(const f32x4*)(qrow + 32 + g * 8 + 4);
    const bf16x8 qfrag0 = {(__bf16)qa[0], (__bf16)qa[1], (__bf16)qa[2], (__bf16)qa[3],
                           (__bf16)qc[0], (__bf16)qc[1], (__bf16)qc[2], (__bf16)qc[3]};
    const bf16x8 qfrag1 = {(__bf16)qe[0], (__bf16)qe[1], (__bf16)qe[2], (__bf16)qe[3],
                           (__bf16)qf[0], (__bf16)qf[1], (__bf16)qf[2], (__bf16)qf[3]};

    // normalizer from kernel A (broadcast across g lanes)
    const float inv_l = 1.0f / Lp[(size_t)bh * TT + q_glob];

    // stage tile 0
    *(bf16x8*)&Kl[0][srow * LDE + sch * 8] =
        *(const bf16x8*)(Kbh + (size_t)srow * DKK + sch * 8);
    *(bf16x8*)&Vl[0][srow * LDE + sch * 8] =
        *(const bf16x8*)(Vbh + (size_t)srow * TT + sch * 8);
    __syncthreads();

    f32x4 oacc[4] = {};            // O^T[d = m*16+4g+r][q_local]
    for (int kt = 0; kt < NKT; ++kt) {
        const int cur = kt & 1;
        const bool more = (kt + 1 < NKT);
        bf16x8 kreg, vreg;
        if (more) {
            kreg = *(const bf16x8*)(Kbh + ((size_t)(kt + 1) * KBLK + srow) * DKK + sch * 8);
            vreg = *(const bf16x8*)(Vbh + (size_t)srow * TT + (kt + 1) * KBLK + sch * 8);
        }
        const float* bp = biasRow + kt * KBLK;
        f32x4 bv[4];
        #pragma unroll
        for (int s = 0; s < 4; ++s) bv[s] = *(const f32x4*)(bp + s * 16 + g * 4);

        f32x4 acc[4] = {};
        #pragma unroll
        for (int s = 0; s < 4; ++s) {
            bf16x8 a0 = *(const bf16x8*)&Kl[cur][(s * 16 + ql) * LDE + g * 8];
            acc[s] = __builtin_amdgcn_mfma_f32_16x16x32_bf16(a0, qfrag0, acc[s], 0, 0, 0);
            bf16x8 a1 = *(const bf16x8*)&Kl[cur][(s * 16 + ql) * LDE + 32 + g * 8];
            acc[s] = __builtin_amdgcn_mfma_f32_16x16x32_bf16(a1, qfrag1, acc[s], 0, 0, 0);
        }
        // P = softmax weights (bf16), wave-private tile
        #pragma unroll
        for (int s = 0; s < 4; ++s) {
            f32x4 x = acc[s] * SCALE + bv[s];
            bf16x4 pb = {(__bf16)(__expf(x[0]) * inv_l), (__bf16)(__expf(x[1]) * inv_l),
                         (__bf16)(__expf(x[2]) * inv_l), (__bf16)(__expf(x[3]) * inv_l)};
            *(bf16x4*)&Pl[w][ql * LDE + s * 16 + g * 4] = pb;
        }
        // PV: read own wave's P fragments (same-wave DS RAW is in-order)
        const bf16x8 bp0 = *(const bf16x8*)&Pl[w][ql * LDE + g * 8];
        const bf16x8 bp1 = *(const bf16x8*)&Pl[w][ql * LDE + 32 + g * 8];
        #pragma unroll
        for (int m = 0; m < 4; ++m) {
            bf16x8 av0 = *(const bf16x8*)&Vl[cur][(m * 16 + ql) * LDE + g * 8];
            oacc[m] = __builtin_amdgcn_mfma_f32_16x16x32_bf16(av0, bp0, oacc[m], 0, 0, 0);
            bf16x8 av1 = *(const bf16x8*)&Vl[cur][(m * 16 + ql) * LDE + 32 + g * 8];
            oacc[m] = __builtin_amdgcn_mfma_f32_16x16x32_bf16(av1, bp1, oacc[m], 0, 0, 0);
        }
        // cooperative W store from Pl: 4 rows x 256B per instr, NONTEMPORAL
        #pragma unroll
        for (int s2 = 0; s2 < 4; ++s2) {
            const int wr = s2 * 4 + g;                 // row 0..15 within wave
            bf16x4 pw = *(const bf16x4*)&Pl[w][wr * LDE + ql * 4];
            f32x4 ow = {(float)pw[0], (float)pw[1], (float)pw[2], (float)pw[3]};
            __builtin_nontemporal_store(ow,
                (f32x4*)(Wp + ((size_t)bh * TT + qt * 128 + w * 16 + wr) * TT
                             + kt * KBLK + ql * 4));
        }
        if (more) {  // write-late staging, then the soft barrier
            *(bf16x8*)&Kl[cur ^ 1][srow * LDE + sch * 8] = kreg;
            *(bf16x8*)&Vl[cur ^ 1][srow * LDE + sch * 8] = vreg;
        }
        SOFT_BARRIER();
    }

    // ---- store O (nontemporal; write-once) ----
    float* Orow = Op + ((size_t)bh * TT + q_glob) * DKK;
    #pragma unroll
    for (int m = 0; m < 4; ++m)
        __builtin_nontemporal_store(oacc[m], (f32x4*)(Orow + m * 16 + g * 4));
}

extern "C" void kernel_launch(void* const* d_in, const int* in_sizes, int n_in,
                              void* d_out, int out_size, void* d_ws, size_t ws_size,
                              hipStream_t stream) {
    const float* Q  = (const float*)d_in[0];
    const float* K  = (const float*)d_in[1];
    const float* V  = (const float*)d_in[2];
    const float* Bs = (const float*)d_in[3];
    float* Out = (float*)d_out;
    float* W   = Out + (size_t)NBB * NHH * TT * DKK;

    const size_t nElem = (size_t)NBB * NHH * TT * DKK;   // 4,194,304
    __bf16* Kb = (__bf16*)d_ws;                          // 8 MB
    __bf16* Vt = Kb + nElem;                             // 8 MB
    float*  Lp = (float*)(Vt + nElem);                   // 256 KB

    cast_k_kernel<<<dim3(nElem / 8 / 256), dim3(256), 0, stream>>>(K, Kb);
    vt_kernel<<<dim3(TT / 64, NBB * NHH), dim3(256), 0, stream>>>(V, Vt);
    lsum_kernel<<<dim3(32 * NBB * NHH), dim3(512), 0, stream>>>(Q, Bs, Kb, Lp);
    sdpa_main<<<dim3(16 * NBB * NHH), dim3(512), 0, stream>>>(Q, Bs, Kb, Vt, Lp, Out, W);
}

// Round 15
// 215.442 us; speedup vs baseline: 1.0324x; 1.0324x over previous
//
#include <hip/hip_runtime.h>
#include <hip/hip_bf16.h>

// SDPA with bias, materializing output + attention weights.
// B=4, H=8, T=2048, DK=64, fp32 in/out, bf16 MFMA 16x16x32 inside.
// Round 15: r13 (best: 205us) + ONE change: phase 2's bias loads go from
// 16-row-scatter (the access shape that cost ~80us as V-direct in r2/r11) to
// fully-coalesced reads of a fragment-ordered bf16 buffer (Bt, 64MB in d_ws)
// that phase 1 emits from its already-loaded values (2x16B coalesced stores,
// thread-private slots). Gated on ws_size; fallback = exact r13 behavior.
#define TT   2048
#define DKK  64
#define NHH  8
#define NBB  4
#define QB   128
#define KBLK 64
#define NKT  (TT / KBLK)   // 32
#define LDE  72            // padded LDS row stride: bank-uniform for frag reads
#define TILE (KBLK * LDE)
#define SCALE 0.125f

// LDS-only barrier: waits own ds ops, syncs waves, does NOT drain vmcnt
#define SOFT_BARRIER() do {                                         \
    asm volatile("s_waitcnt lgkmcnt(0)" ::: "memory");              \
    __builtin_amdgcn_s_barrier();                                   \
    asm volatile("" ::: "memory");                                  \
} while (0)

typedef __attribute__((ext_vector_type(4))) float  f32x4;
typedef __attribute__((ext_vector_type(8))) __bf16 bf16x8;
typedef __attribute__((ext_vector_type(4))) __bf16 bf16x4;

// ---- prepass 1: K fp32 -> bf16, same [bh][t][d] layout ----
__global__ __launch_bounds__(256)
void cast_k_kernel(const float* __restrict__ K, __bf16* __restrict__ Kb) {
    size_t i = ((size_t)blockIdx.x * 256 + threadIdx.x) * 8;
    f32x4 a = *(const f32x4*)(K + i);
    f32x4 b = *(const f32x4*)(K + i + 4);
    bf16x8 o = {(__bf16)a[0], (__bf16)a[1], (__bf16)a[2], (__bf16)a[3],
                (__bf16)b[0], (__bf16)b[1], (__bf16)b[2], (__bf16)b[3]};
    *(bf16x8*)(Kb + i) = o;
}

// ---- prepass 2: V fp32 [bh][t][d] -> bf16 transposed [bh][d][t] ----
__global__ __launch_bounds__(256)
void vt_kernel(const float* __restrict__ V, __bf16* __restrict__ Vt) {
    __shared__ __bf16 tile[DKK][72];
    const int bh = blockIdx.y;
    const int t0 = blockIdx.x * 64;
    const int tid = threadIdx.x;
    const float* Vb = V + ((size_t)bh * TT + t0) * DKK;
    #pragma unroll
    for (int i = 0; i < 4; ++i) {
        int idx = tid + i * 256;
        int row = idx >> 4, c4 = idx & 15;
        f32x4 v = *(const f32x4*)(Vb + row * DKK + c4 * 4);
        tile[c4 * 4 + 0][row] = (__bf16)v[0];
        tile[c4 * 4 + 1][row] = (__bf16)v[1];
        tile[c4 * 4 + 2][row] = (__bf16)v[2];
        tile[c4 * 4 + 3][row] = (__bf16)v[3];
    }
    __syncthreads();
    __bf16* out = Vt + (size_t)bh * DKK * TT + t0;
    #pragma unroll
    for (int i = 0; i < 2; ++i) {
        int idx = tid + i * 256;
        int d = idx >> 3, ch = idx & 7;
        bf16x8 o = *(const bf16x8*)&tile[d][ch * 8];
        *(bf16x8*)(out + (size_t)d * TT + ch * 8) = o;
    }
}

// ---- main: 8 q-waves, 128 q-rows/block, 1 soft barrier per k-iteration ----
__global__ __launch_bounds__(512, 4)
void sdpa_main(const float* __restrict__ Qp, const float* __restrict__ Bp,
               const __bf16* __restrict__ Kb, const __bf16* __restrict__ Vt,
               __bf16* __restrict__ Bt,      // fragment-ordered bias (or null)
               float* __restrict__ Op, float* __restrict__ Wp)
{
    __shared__ __bf16 Kl[2][TILE];     // K tile double buffer [key][d]
    __shared__ __bf16 Vl[2][TILE];     // V^T tile double buffer [d][key]
    __shared__ __bf16 Pl[8][16 * LDE]; // wave-private P [q][key]

    const int tid  = threadIdx.x;
    const int lane = tid & 63;
    const int w    = tid >> 6;     // 0..7 : q rows w*16..+15
    const int g    = lane >> 4;    // 0..3
    const int ql   = lane & 15;

    // XCD-aware decode: h = id&7 pins each head's bias slice to one XCD.
    const int id  = blockIdx.x;    // 0..511
    const int h   = id & 7;
    const int r   = id >> 3;       // 0..63
    const int qt  = r & 15;        // 0..15
    const int b   = r >> 4;        // 0..3
    const int bh  = b * NHH + h;

    const int q_local = w * 16 + ql;
    const int q_glob  = qt * QB + q_local;

    const __bf16* Kbh = Kb + (size_t)bh * TT * DKK;   // [key][d]
    const __bf16* Vbh = Vt + (size_t)bh * DKK * TT;   // [d][key]
    const float* biasRow = Bp + ((size_t)h * TT + q_glob) * TT;
    // per-(h,qt) fragment-bias slab: 32 kt x 8192 bf16 (16KB each)
    __bf16* BtSlab = Bt ? (Bt + (size_t)(h * 16 + qt) * NKT * 8192) : nullptr;

    // staging map: 512 threads x 16B = one 64x64 bf16 tile
    const int srow = tid >> 3;     // 0..63
    const int sch  = tid & 7;      // 0..7

    // Q fragments (B-operand): lane holds Q[q_glob][d = 8g+j (+32)]
    const float* qrow = Qp + ((size_t)bh * TT + q_glob) * DKK;
    f32x4 qa = *(const f32x4*)(qrow + g * 8);
    f32x4 qc = *(const f32x4*)(qrow + g * 8 + 4);
    f32x4 qe = *(const f32x4*)(qrow + 32 + g * 8);
    f32x4 qf = *(const f32x4*)(qrow + 32 + g * 8 + 4);
    const bf16x8 qfrag0 = {(__bf16)qa[0], (__bf16)qa[1], (__bf16)qa[2], (__bf16)qa[3],
                           (__bf16)qc[0], (__bf16)qc[1], (__bf16)qc[2], (__bf16)qc[3]};
    const bf16x8 qfrag1 = {(__bf16)qe[0], (__bf16)qe[1], (__bf16)qe[2], (__bf16)qe[3],
                           (__bf16)qf[0], (__bf16)qf[1], (__bf16)qf[2], (__bf16)qf[3]};

    // ================= phase 1: l = sum exp(s) over all keys =============
    *(bf16x8*)&Kl[0][srow * LDE + sch * 8] =
        *(const bf16x8*)(Kbh + (size_t)srow * DKK + sch * 8);
    __syncthreads();

    f32x4 lacc = {0.f, 0.f, 0.f, 0.f};
    for (int kt = 0; kt < NKT; ++kt) {
        const int cur = kt & 1;
        const bool more = (kt + 1 < NKT);
        bf16x8 kreg;
        if (more)  // prefetch next K tile into regs (issue early)
            kreg = *(const bf16x8*)(Kbh + ((size_t)(kt + 1) * KBLK + srow) * DKK + sch * 8);
        const float* bp = biasRow + kt * KBLK;
        f32x4 bv[4];
        #pragma unroll
        for (int s = 0; s < 4; ++s) bv[s] = *(const f32x4*)(bp + s * 16 + g * 4);

        f32x4 acc[4] = {};
        #pragma unroll
        for (int s = 0; s < 4; ++s) {
            bf16x8 a0 = *(const bf16x8*)&Kl[cur][(s * 16 + ql) * LDE + g * 8];
            acc[s] = __builtin_amdgcn_mfma_f32_16x16x32_bf16(a0, qfrag0, acc[s], 0, 0, 0);
            bf16x8 a1 = *(const bf16x8*)&Kl[cur][(s * 16 + ql) * LDE + 32 + g * 8];
            acc[s] = __builtin_amdgcn_mfma_f32_16x16x32_bf16(a1, qfrag1, acc[s], 0, 0, 0);
        }
        // emit fragment-ordered bf16 bias for phase 2 (coalesced, thread-private)
        if (BtSlab) {
            __bf16* bt = BtSlab + (size_t)kt * 8192;
            bf16x8 b0 = {(__bf16)bv[0][0], (__bf16)bv[0][1], (__bf16)bv[0][2], (__bf16)bv[0][3],
                         (__bf16)bv[1][0], (__bf16)bv[1][1], (__bf16)bv[1][2], (__bf16)bv[1][3]};
            bf16x8 b1 = {(__bf16)bv[2][0], (__bf16)bv[2][1], (__bf16)bv[2][2], (__bf16)bv[2][3],
                         (__bf16)bv[3][0], (__bf16)bv[3][1], (__bf16)bv[3][2], (__bf16)bv[3][3]};
            *(bf16x8*)(bt + tid * 8) = b0;
            *(bf16x8*)(bt + 4096 + tid * 8) = b1;
        }
        #pragma unroll
        for (int s = 0; s < 4; ++s) {
            f32x4 x = acc[s] * SCALE + bv[s];
            lacc[0] += __expf(x[0]);
            lacc[1] += __expf(x[1]);
            lacc[2] += __expf(x[2]);
            lacc[3] += __expf(x[3]);
        }
        if (more)  // write-late: latency hidden under this iter's compute
            *(bf16x8*)&Kl[cur ^ 1][srow * LDE + sch * 8] = kreg;
        SOFT_BARRIER();
    }
    float l_run = lacc[0] + lacc[1] + lacc[2] + lacc[3];
    l_run += __shfl_xor(l_run, 16);
    l_run += __shfl_xor(l_run, 32);
    const float inv_l = 1.0f / l_run;

    // ================= phase 2: recompute, write W, accumulate PV ========
    *(bf16x8*)&Kl[0][srow * LDE + sch * 8] =
        *(const bf16x8*)(Kbh + (size_t)srow * DKK + sch * 8);
    *(bf16x8*)&Vl[0][srow * LDE + sch * 8] =
        *(const bf16x8*)(Vbh + (size_t)srow * TT + sch * 8);
    __syncthreads();   // hard barrier: also drains phase-1 Bt stores (vmcnt 0)

    f32x4 oacc[4] = {};            // O^T[d = m*16+4g+r][q_local]
    for (int kt = 0; kt < NKT; ++kt) {
        const int cur = kt & 1;
        const bool more = (kt + 1 < NKT);
        bf16x8 kreg, vreg;
        if (more) {
            kreg = *(const bf16x8*)(Kbh + ((size_t)(kt + 1) * KBLK + srow) * DKK + sch * 8);
            vreg = *(const bf16x8*)(Vbh + (size_t)srow * TT + (kt + 1) * KBLK + sch * 8);
        }
        f32x4 bv[4];
        if (BtSlab) {
            // coalesced fragment-ordered bias: 2x16B per thread
            const __bf16* bt = BtSlab + (size_t)kt * 8192;
            bf16x8 b0 = *(const bf16x8*)(bt + tid * 8);
            bf16x8 b1 = *(const bf16x8*)(bt + 4096 + tid * 8);
            bv[0] = f32x4{(float)b0[0], (float)b0[1], (float)b0[2], (float)b0[3]};
            bv[1] = f32x4{(float)b0[4], (float)b0[5], (float)b0[6], (float)b0[7]};
            bv[2] = f32x4{(float)b1[0], (float)b1[1], (float)b1[2], (float)b1[3]};
            bv[3] = f32x4{(float)b1[4], (float)b1[5], (float)b1[6], (float)b1[7]};
        } else {
            const float* bp = biasRow + kt * KBLK;
            #pragma unroll
            for (int s = 0; s < 4; ++s) bv[s] = *(const f32x4*)(bp + s * 16 + g * 4);
        }

        f32x4 acc[4] = {};
        #pragma unroll
        for (int s = 0; s < 4; ++s) {
            bf16x8 a0 = *(const bf16x8*)&Kl[cur][(s * 16 + ql) * LDE + g * 8];
            acc[s] = __builtin_amdgcn_mfma_f32_16x16x32_bf16(a0, qfrag0, acc[s], 0, 0, 0);
            bf16x8 a1 = *(const bf16x8*)&Kl[cur][(s * 16 + ql) * LDE + 32 + g * 8];
            acc[s] = __builtin_amdgcn_mfma_f32_16x16x32_bf16(a1, qfrag1, acc[s], 0, 0, 0);
        }
        // P = softmax weights (bf16), wave-private tile
        #pragma unroll
        for (int s = 0; s < 4; ++s) {
            f32x4 x = acc[s] * SCALE + bv[s];
            bf16x4 pb = {(__bf16)(__expf(x[0]) * inv_l), (__bf16)(__expf(x[1]) * inv_l),
                         (__bf16)(__expf(x[2]) * inv_l), (__bf16)(__expf(x[3]) * inv_l)};
            *(bf16x4*)&Pl[w][ql * LDE + s * 16 + g * 4] = pb;
        }
        // PV: read own wave's P fragments (same-wave DS RAW is in-order)
        const bf16x8 bp0 = *(const bf16x8*)&Pl[w][ql * LDE + g * 8];
        const bf16x8 bp1 = *(const bf16x8*)&Pl[w][ql * LDE + 32 + g * 8];
        #pragma unroll
        for (int m = 0; m < 4; ++m) {
            bf16x8 av0 = *(const bf16x8*)&Vl[cur][(m * 16 + ql) * LDE + g * 8];
            oacc[m] = __builtin_amdgcn_mfma_f32_16x16x32_bf16(av0, bp0, oacc[m], 0, 0, 0);
            bf16x8 av1 = *(const bf16x8*)&Vl[cur][(m * 16 + ql) * LDE + 32 + g * 8];
            oacc[m] = __builtin_amdgcn_mfma_f32_16x16x32_bf16(av1, bp1, oacc[m], 0, 0, 0);
        }
        // cooperative W store from Pl: 4 rows x 256B per instr, NONTEMPORAL
        #pragma unroll
        for (int s2 = 0; s2 < 4; ++s2) {
            const int wr = s2 * 4 + g;                 // row 0..15 within wave
            bf16x4 pw = *(const bf16x4*)&Pl[w][wr * LDE + ql * 4];
            f32x4 ow = {(float)pw[0], (float)pw[1], (float)pw[2], (float)pw[3]};
            __builtin_nontemporal_store(ow,
                (f32x4*)(Wp + ((size_t)bh * TT + qt * QB + w * 16 + wr) * TT
                             + kt * KBLK + ql * 4));
        }
        if (more) {  // write-late staging, then the soft barrier
            *(bf16x8*)&Kl[cur ^ 1][srow * LDE + sch * 8] = kreg;
            *(bf16x8*)&Vl[cur ^ 1][srow * LDE + sch * 8] = vreg;
        }
        SOFT_BARRIER();
    }

    // ---- store O (nontemporal; write-once) ----
    float* Orow = Op + ((size_t)bh * TT + q_glob) * DKK;
    #pragma unroll
    for (int m = 0; m < 4; ++m)
        __builtin_nontemporal_store(oacc[m], (f32x4*)(Orow + m * 16 + g * 4));
}

extern "C" void kernel_launch(void* const* d_in, const int* in_sizes, int n_in,
                              void* d_out, int out_size, void* d_ws, size_t ws_size,
                              hipStream_t stream) {
    const float* Q  = (const float*)d_in[0];
    const float* K  = (const float*)d_in[1];
    const float* V  = (const float*)d_in[2];
    const float* Bs = (const float*)d_in[3];
    float* Out = (float*)d_out;
    float* W   = Out + (size_t)NBB * NHH * TT * DKK;

    const size_t nElem = (size_t)NBB * NHH * TT * DKK;   // 4,194,304
    __bf16* Kb = (__bf16*)d_ws;                          // 8 MB
    __bf16* Vt = Kb + nElem;                             // 8 MB
    // fragment-ordered bias: 8 h x 16 qt x 32 kt x 8192 bf16 = 64 MB
    const size_t btElems = (size_t)NHH * 16 * NKT * 8192;
    const size_t need = 2 * nElem * sizeof(__bf16) + btElems * sizeof(__bf16);
    __bf16* Bt = (ws_size >= need) ? (Vt + nElem) : nullptr;

    cast_k_kernel<<<dim3(nElem / 8 / 256), dim3(256), 0, stream>>>(K, Kb);
    vt_kernel<<<dim3(TT / 64, NBB * NHH), dim3(256), 0, stream>>>(V, Vt);
    sdpa_main<<<dim3((TT / QB) * NBB * NHH), dim3(512), 0, stream>>>(Q, Bs, Kb, Vt, Bt, Out, W);
}

// Round 17
// 202.208 us; speedup vs baseline: 1.1000x; 1.0654x over previous
//
#include <hip/hip_runtime.h>
#include <hip/hip_bf16.h>

// SDPA with bias, materializing output + attention weights.
// B=4, H=8, T=2048, DK=64, fp32 in/out, bf16 MFMA 16x16x32 inside.
// Round 17: r16's intent, race-free. Phase 1 processes 2 tiles/iter with PAIR
// ping-pong: even iters read Bl[0..1], odd read Bl[2..3]; 2-deep prefetch
// writes the OTHER pair (write-late after the barrier that retired its reads
// -- the r5 safety argument r16 violated). Barriers 32->16, l bit-identical
// to r13. Phase 2 = r13 byte-identical (buffers renamed). NT W/O stores kept.
#define TT   2048
#define DKK  64
#define NHH  8
#define NBB  4
#define QB   128
#define KBLK 64
#define NKT  (TT / KBLK)   // 32
#define NJ1  (NKT / 2)     // 16 phase-1 iterations, 2 tiles each
#define LDE  72            // padded LDS row stride: bank-uniform for frag reads
#define TILE (KBLK * LDE)
#define SCALE 0.125f

// LDS-only barrier: waits own ds ops, syncs waves, does NOT drain vmcnt
#define SOFT_BARRIER() do {                                         \
    asm volatile("s_waitcnt lgkmcnt(0)" ::: "memory");              \
    __builtin_amdgcn_s_barrier();                                   \
    asm volatile("" ::: "memory");                                  \
} while (0)

typedef __attribute__((ext_vector_type(4))) float  f32x4;
typedef __attribute__((ext_vector_type(8))) __bf16 bf16x8;
typedef __attribute__((ext_vector_type(4))) __bf16 bf16x4;

// ---- prepass 1: K fp32 -> bf16, same [bh][t][d] layout ----
__global__ __launch_bounds__(256)
void cast_k_kernel(const float* __restrict__ K, __bf16* __restrict__ Kb) {
    size_t i = ((size_t)blockIdx.x * 256 + threadIdx.x) * 8;
    f32x4 a = *(const f32x4*)(K + i);
    f32x4 b = *(const f32x4*)(K + i + 4);
    bf16x8 o = {(__bf16)a[0], (__bf16)a[1], (__bf16)a[2], (__bf16)a[3],
                (__bf16)b[0], (__bf16)b[1], (__bf16)b[2], (__bf16)b[3]};
    *(bf16x8*)(Kb + i) = o;
}

// ---- prepass 2: V fp32 [bh][t][d] -> bf16 transposed [bh][d][t] ----
__global__ __launch_bounds__(256)
void vt_kernel(const float* __restrict__ V, __bf16* __restrict__ Vt) {
    __shared__ __bf16 tile[DKK][72];
    const int bh = blockIdx.y;
    const int t0 = blockIdx.x * 64;
    const int tid = threadIdx.x;
    const float* Vb = V + ((size_t)bh * TT + t0) * DKK;
    #pragma unroll
    for (int i = 0; i < 4; ++i) {
        int idx = tid + i * 256;
        int row = idx >> 4, c4 = idx & 15;
        f32x4 v = *(const f32x4*)(Vb + row * DKK + c4 * 4);
        tile[c4 * 4 + 0][row] = (__bf16)v[0];
        tile[c4 * 4 + 1][row] = (__bf16)v[1];
        tile[c4 * 4 + 2][row] = (__bf16)v[2];
        tile[c4 * 4 + 3][row] = (__bf16)v[3];
    }
    __syncthreads();
    __bf16* out = Vt + (size_t)bh * DKK * TT + t0;
    #pragma unroll
    for (int i = 0; i < 2; ++i) {
        int idx = tid + i * 256;
        int d = idx >> 3, ch = idx & 7;
        bf16x8 o = *(const bf16x8*)&tile[d][ch * 8];
        *(bf16x8*)(out + (size_t)d * TT + ch * 8) = o;
    }
}

// ---- main: 8 q-waves, 128 q-rows/block ----
__global__ __launch_bounds__(512, 4)
void sdpa_main(const float* __restrict__ Qp, const float* __restrict__ Bp,
               const __bf16* __restrict__ Kb, const __bf16* __restrict__ Vt,
               float* __restrict__ Op, float* __restrict__ Wp)
{
    __shared__ __bf16 Bl[4][TILE];     // ph1: two K pairs; ph2: [0..1]=K, [2..3]=V
    __shared__ __bf16 Pl[8][16 * LDE]; // wave-private P [q][key]

    const int tid  = threadIdx.x;
    const int lane = tid & 63;
    const int w    = tid >> 6;     // 0..7 : q rows w*16..+15
    const int g    = lane >> 4;    // 0..3
    const int ql   = lane & 15;

    // XCD-aware decode: h = id&7 pins each head's bias slice to one XCD.
    const int id  = blockIdx.x;    // 0..511
    const int h   = id & 7;
    const int r   = id >> 3;       // 0..63
    const int qt  = r & 15;        // 0..15
    const int b   = r >> 4;        // 0..3
    const int bh  = b * NHH + h;

    const int q_local = w * 16 + ql;
    const int q_glob  = qt * QB + q_local;

    const __bf16* Kbh = Kb + (size_t)bh * TT * DKK;   // [key][d]
    const __bf16* Vbh = Vt + (size_t)bh * DKK * TT;   // [d][key]
    const float* biasRow = Bp + ((size_t)h * TT + q_glob) * TT;

    // staging map: 512 threads x 16B = one 64x64 bf16 tile
    const int srow = tid >> 3;     // 0..63
    const int sch  = tid & 7;      // 0..7

    // Q fragments (B-operand): lane holds Q[q_glob][d = 8g+j (+32)]
    const float* qrow = Qp + ((size_t)bh * TT + q_glob) * DKK;
    f32x4 qa = *(const f32x4*)(qrow + g * 8);
    f32x4 qc = *(const f32x4*)(qrow + g * 8 + 4);
    f32x4 qe = *(const f32x4*)(qrow + 32 + g * 8);
    f32x4 qf = *(const f32x4*)(qrow + 32 + g * 8 + 4);
    const bf16x8 qfrag0 = {(__bf16)qa[0], (__bf16)qa[1], (__bf16)qa[2], (__bf16)qa[3],
                           (__bf16)qc[0], (__bf16)qc[1], (__bf16)qc[2], (__bf16)qc[3]};
    const bf16x8 qfrag1 = {(__bf16)qe[0], (__bf16)qe[1], (__bf16)qe[2], (__bf16)qe[3],
                           (__bf16)qf[0], (__bf16)qf[1], (__bf16)qf[2], (__bf16)qf[3]};

    // ========== phase 1: l = sum exp(s); 2 tiles/iter, pair ping-pong =====
    #pragma unroll
    for (int t = 0; t < 2; ++t) {
        *(bf16x8*)&Bl[t][srow * LDE + sch * 8] =
            *(const bf16x8*)(Kbh + ((size_t)t * KBLK + srow) * DKK + sch * 8);
    }
    __syncthreads();

    f32x4 lacc = {0.f, 0.f, 0.f, 0.f};
    for (int j = 0; j < NJ1; ++j) {
        const int pc = (j & 1) * 2;        // pair being read this iteration
        const int pn = ((j + 1) & 1) * 2;  // pair to fill for next iteration
        const bool more = (j + 1 < NJ1);
        bf16x8 kregs[2];
        if (more) {   // 2-deep prefetch (2x MLP on the latency path)
            #pragma unroll
            for (int t = 0; t < 2; ++t)
                kregs[t] = *(const bf16x8*)(Kbh +
                    ((size_t)((j + 1) * 2 + t) * KBLK + srow) * DKK + sch * 8);
        }
        #pragma unroll
        for (int t = 0; t < 2; ++t) {
            const int kt = j * 2 + t;
            const float* bp = biasRow + kt * KBLK;
            f32x4 bv[4];
            #pragma unroll
            for (int s = 0; s < 4; ++s) bv[s] = *(const f32x4*)(bp + s * 16 + g * 4);
            f32x4 acc[4] = {};
            #pragma unroll
            for (int s = 0; s < 4; ++s) {
                bf16x8 a0 = *(const bf16x8*)&Bl[pc + t][(s * 16 + ql) * LDE + g * 8];
                acc[s] = __builtin_amdgcn_mfma_f32_16x16x32_bf16(a0, qfrag0, acc[s], 0, 0, 0);
                bf16x8 a1 = *(const bf16x8*)&Bl[pc + t][(s * 16 + ql) * LDE + 32 + g * 8];
                acc[s] = __builtin_amdgcn_mfma_f32_16x16x32_bf16(a1, qfrag1, acc[s], 0, 0, 0);
            }
            #pragma unroll
            for (int s = 0; s < 4; ++s) {
                f32x4 x = acc[s] * SCALE + bv[s];
                lacc[0] += __expf(x[0]);
                lacc[1] += __expf(x[1]);
                lacc[2] += __expf(x[2]);
                lacc[3] += __expf(x[3]);
            }
        }
        if (more) {   // write-late into the OTHER pair (reads of it retired
                      // at the previous barrier) -- WAR-safe like r5
            #pragma unroll
            for (int t = 0; t < 2; ++t)
                *(bf16x8*)&Bl[pn + t][srow * LDE + sch * 8] = kregs[t];
        }
        SOFT_BARRIER();
    }
    float l_run = lacc[0] + lacc[1] + lacc[2] + lacc[3];
    l_run += __shfl_xor(l_run, 16);
    l_run += __shfl_xor(l_run, 32);
    const float inv_l = 1.0f / l_run;

    // ================= phase 2: recompute, write W, accumulate PV ========
    // buffers: Bl[0..1] = K double buffer, Bl[2..3] = V^T double buffer
    __syncthreads();               // all phase-1 reads done before restaging
    *(bf16x8*)&Bl[0][srow * LDE + sch * 8] =
        *(const bf16x8*)(Kbh + (size_t)srow * DKK + sch * 8);
    *(bf16x8*)&Bl[2][srow * LDE + sch * 8] =
        *(const bf16x8*)(Vbh + (size_t)srow * TT + sch * 8);
    __syncthreads();

    f32x4 oacc[4] = {};            // O^T[d = m*16+4g+r][q_local]
    for (int kt = 0; kt < NKT; ++kt) {
        const int cur = kt & 1;
        const bool more = (kt + 1 < NKT);
        bf16x8 kreg, vreg;
        if (more) {
            kreg = *(const bf16x8*)(Kbh + ((size_t)(kt + 1) * KBLK + srow) * DKK + sch * 8);
            vreg = *(const bf16x8*)(Vbh + (size_t)srow * TT + (kt + 1) * KBLK + sch * 8);
        }
        const float* bp = biasRow + kt * KBLK;
        f32x4 bv[4];
        #pragma unroll
        for (int s = 0; s < 4; ++s) bv[s] = *(const f32x4*)(bp + s * 16 + g * 4);

        f32x4 acc[4] = {};
        #pragma unroll
        for (int s = 0; s < 4; ++s) {
            bf16x8 a0 = *(const bf16x8*)&Bl[cur][(s * 16 + ql) * LDE + g * 8];
            acc[s] = __builtin_amdgcn_mfma_f32_16x16x32_bf16(a0, qfrag0, acc[s], 0, 0, 0);
            bf16x8 a1 = *(const bf16x8*)&Bl[cur][(s * 16 + ql) * LDE + 32 + g * 8];
            acc[s] = __builtin_amdgcn_mfma_f32_16x16x32_bf16(a1, qfrag1, acc[s], 0, 0, 0);
        }
        // P = softmax weights (bf16), wave-private tile
        #pragma unroll
        for (int s = 0; s < 4; ++s) {
            f32x4 x = acc[s] * SCALE + bv[s];
            bf16x4 pb = {(__bf16)(__expf(x[0]) * inv_l), (__bf16)(__expf(x[1]) * inv_l),
                         (__bf16)(__expf(x[2]) * inv_l), (__bf16)(__expf(x[3]) * inv_l)};
            *(bf16x4*)&Pl[w][ql * LDE + s * 16 + g * 4] = pb;
        }
        // PV: read own wave's P fragments (same-wave DS RAW is in-order)
        const bf16x8 bp0 = *(const bf16x8*)&Pl[w][ql * LDE + g * 8];
        const bf16x8 bp1 = *(const bf16x8*)&Pl[w][ql * LDE + 32 + g * 8];
        #pragma unroll
        for (int m = 0; m < 4; ++m) {
            bf16x8 av0 = *(const bf16x8*)&Bl[2 + cur][(m * 16 + ql) * LDE + g * 8];
            oacc[m] = __builtin_amdgcn_mfma_f32_16x16x32_bf16(av0, bp0, oacc[m], 0, 0, 0);
            bf16x8 av1 = *(const bf16x8*)&Bl[2 + cur][(m * 16 + ql) * LDE + 32 + g * 8];
            oacc[m] = __builtin_amdgcn_mfma_f32_16x16x32_bf16(av1, bp1, oacc[m], 0, 0, 0);
        }
        // cooperative W store from Pl: 4 rows x 256B per instr, NONTEMPORAL
        #pragma unroll
        for (int s2 = 0; s2 < 4; ++s2) {
            const int wr = s2 * 4 + g;                 // row 0..15 within wave
            bf16x4 pw = *(const bf16x4*)&Pl[w][wr * LDE + ql * 4];
            f32x4 ow = {(float)pw[0], (float)pw[1], (float)pw[2], (float)pw[3]};
            __builtin_nontemporal_store(ow,
                (f32x4*)(Wp + ((size_t)bh * TT + qt * QB + w * 16 + wr) * TT
                             + kt * KBLK + ql * 4));
        }
        if (more) {  // write-late staging into cur^1 (WAR-safe), then barrier
            *(bf16x8*)&Bl[cur ^ 1][srow * LDE + sch * 8] = kreg;
            *(bf16x8*)&Bl[2 + (cur ^ 1)][srow * LDE + sch * 8] = vreg;
        }
        SOFT_BARRIER();
    }

    // ---- store O (nontemporal; write-once) ----
    float* Orow = Op + ((size_t)bh * TT + q_glob) * DKK;
    #pragma unroll
    for (int m = 0; m < 4; ++m)
        __builtin_nontemporal_store(oacc[m], (f32x4*)(Orow + m * 16 + g * 4));
}

extern "C" void kernel_launch(void* const* d_in, const int* in_sizes, int n_in,
                              void* d_out, int out_size, void* d_ws, size_t ws_size,
                              hipStream_t stream) {
    const float* Q  = (const float*)d_in[0];
    const float* K  = (const float*)d_in[1];
    const float* V  = (const float*)d_in[2];
    const float* Bs = (const float*)d_in[3];
    float* Out = (float*)d_out;
    float* W   = Out + (size_t)NBB * NHH * TT * DKK;

    const size_t nElem = (size_t)NBB * NHH * TT * DKK;
    __bf16* Kb = (__bf16*)d_ws;
    __bf16* Vt = Kb + nElem;

    cast_k_kernel<<<dim3(nElem / 8 / 256), dim3(256), 0, stream>>>(K, Kb);
    vt_kernel<<<dim3(TT / 64, NBB * NHH), dim3(256), 0, stream>>>(V, Vt);
    sdpa_main<<<dim3((TT / QB) * NBB * NHH), dim3(512), 0, stream>>>(Q, Bs, Kb, Vt, Out, W);
}